// Round 3
// baseline (178.058 us; speedup 1.0000x reference)
//
#include <hip/hip_runtime.h>

// ---------------------------------------------------------------------------
// UniversalBlockEncoder: algebraically folded attention pooling.
//
//   u_i = silu(W1 x_i + b1)                 (the only per-point nonlinearity)
//   s_h(i) = g_h . u_i + d_h    with g_h = W2^T (scale Wk_h^T q_h)
//   p = exp(s)  (scores O(3), f32-safe without max-subtraction)
//   T_h = sum_i p_h(i) u_i ,  l_h = sum_i p_h(i)
//   out = Wo ( Wv ( W2 (T/l) + b2 ) + bv ) + bo
//
// R3: wide setup kernel, MFMA T-phase (16x16x32 bf16), finish folded into
//     main via last-block counter.
// ---------------------------------------------------------------------------

#define LOG2E 1.44269504088896340736f
#define NLN2  (-0.69314718055994530942f)

#if __has_builtin(__builtin_amdgcn_exp2f)
#define EXP2(x) __builtin_amdgcn_exp2f(x)
#else
#define EXP2(x) exp2f(x)
#endif
#if __has_builtin(__builtin_amdgcn_rcpf)
#define RCP(x) __builtin_amdgcn_rcpf(x)
#else
#define RCP(x) (1.0f / (x))
#endif

typedef __attribute__((ext_vector_type(8))) __bf16 bf16x8;
typedef __attribute__((ext_vector_type(4))) float  f32x4;

// workspace float offsets
#define WS_C4   0      // 64 x float4 : {-log2e*W1[j][0], -log2e*W1[j][1], -log2e*b1[j], 0}
#define WS_G4   256    // 64 x float4 : log2e * g_h[j]
#define WS_D    512    // 4           : log2e * d_h
#define WS_ACC  768    // NSLOT x SLOTSTRIDE: [0..3]=l_h, [4+h*64+j]=T_h[j]
#define NSLOT      32
#define SLOTSTRIDE 272
#define WS_CNT  (WS_ACC + NSLOT * SLOTSTRIDE)     // completion counter (int)

#define NPTS       (1024 * 1024)
#define NGROUPS    (NPTS / 64)
#define K1_BLOCKS  2048
#define K1_THREADS 128
#define WAVES_TOTAL (K1_BLOCKS * 2)               // 4096
#define GROUPS_PER_WAVE (NGROUPS / WAVES_TOTAL)   // 4

#define WG_FENCE() __builtin_amdgcn_fence(__ATOMIC_ACQ_REL, "workgroup")

__device__ __forceinline__ unsigned short to_bf16(float x) {
    return (unsigned short)((__float_as_uint(x) + 0x8000u) >> 16);
}

// ---------------------------------------------------------------------------
// Setup: 64 blocks x 64 threads (1 wave). Every block redundantly computes
// q and a (coalesced, parallel); block j computes g[j][h] lane-per-d +
// shuffle reduce. No long serial latency chains.
__global__ void setup_kernel(const float* __restrict__ W1, const float* __restrict__ b1,
                             const float* __restrict__ W2, const float* __restrict__ b2,
                             const float* __restrict__ query,
                             const float* __restrict__ ipw, const float* __restrict__ ipb,
                             float* __restrict__ ws)
{
    __shared__ float qv[64], qs[64], as4[4][64];
    const int t = threadIdx.x;
    const int b = blockIdx.x;     // = output j

    qv[t] = query[t];
    __syncthreads();

    // q[t] = ipw row t . query + ipb[t]
    {
        float a = ipb[t];
        #pragma unroll
        for (int k = 0; k < 64; ++k) a = fmaf(ipw[t * 64 + k], qv[k], a);
        qs[t] = a;
    }
    __syncthreads();

    // a_h[t] = 0.25 * sum_m Wk[h*16+m][t] q[h*16+m]   (coalesced across t)
    #pragma unroll
    for (int h = 0; h < 4; ++h) {
        float a = 0.0f;
        #pragma unroll
        for (int m = 0; m < 16; ++m)
            a = fmaf(ipw[(64 + h * 16 + m) * 64 + t], qs[h * 16 + m], a);
        as4[h][t] = 0.25f * a;
    }
    __syncthreads();

    // g[j=b][h] = sum_d a_h[d] W2[d][b]  : lane d holds one product, shuffle-reduce
    const float w2 = W2[t * 64 + b];
    float g[4];
    #pragma unroll
    for (int h = 0; h < 4; ++h) {
        float v = as4[h][t] * w2;
        for (int m = 1; m < 64; m <<= 1) v += __shfl_xor(v, m);
        g[h] = v;
    }
    if (t == 0) {
        ws[WS_G4 + b * 4 + 0] = LOG2E * g[0];
        ws[WS_G4 + b * 4 + 1] = LOG2E * g[1];
        ws[WS_G4 + b * 4 + 2] = LOG2E * g[2];
        ws[WS_G4 + b * 4 + 3] = LOG2E * g[3];
        ws[WS_C4 + b * 4 + 0] = -LOG2E * W1[2 * b];
        ws[WS_C4 + b * 4 + 1] = -LOG2E * W1[2 * b + 1];
        ws[WS_C4 + b * 4 + 2] = -LOG2E * b1[b];
        ws[WS_C4 + b * 4 + 3] = 0.0f;
    }
    if (b == 0 && t < 4) {
        float d = 0.0f;
        #pragma unroll
        for (int c = 0; c < 64; ++c) d += as4[t][c] * b2[c];
        float qb = 0.0f;
        #pragma unroll
        for (int m = 0; m < 16; ++m) qb += qs[t * 16 + m] * ipb[64 + t * 16 + m];
        ws[WS_D + t] = LOG2E * (d + 0.25f * qb);
    }
}

// ---------------------------------------------------------------------------
// Main: 2 independent waves/block. Phase 1 (lane=point): u via silu, scores,
// stage bf16 u [j][pt] and bf16 p [h][pt]. Phase 2: T accumulated with
// mfma_f32_16x16x32_bf16 (A=p rows 0..3, rows 4..15 garbage/ignored; B=u).
// Last block reduces + applies the output head.
__global__ __launch_bounds__(K1_THREADS, 4) void main_kernel(
        const float* __restrict__ rr, const float* __restrict__ ri,
        const float4* __restrict__ c4g, const float4* __restrict__ g4g,
        const float* __restrict__ dvec, float* __restrict__ accb, int* __restrict__ cnt,
        const float* __restrict__ W2, const float* __restrict__ b2,
        const float* __restrict__ ipw, const float* __restrict__ ipb,
        const float* __restrict__ opw, const float* __restrict__ opb,
        float* __restrict__ out)
{
    __shared__ __align__(16) unsigned short us[2][64 * 72];  // u bf16 [j][pt], stride 72
    __shared__ __align__(16) unsigned short ps[2][4 * 72];   // p bf16 [h][pt]

    const int t    = threadIdx.x;
    const int lane = t & 63;
    const int w    = t >> 6;
    const int quad = lane >> 4;

    unsigned short* uw = us[w];
    unsigned short* pw = ps[w];

    const float d0 = dvec[0], d1 = dvec[1], d2 = dvec[2], d3 = dvec[3];

    const int gwave = blockIdx.x * 2 + w;
    float l0 = 0, l1 = 0, l2 = 0, l3 = 0;
    f32x4 acc[4];
    #pragma unroll
    for (int i = 0; i < 4; ++i) acc[i] = (f32x4){0.f, 0.f, 0.f, 0.f};

    const unsigned short* pa = pw + (lane & 3) * 72 + quad * 8;  // A-frag base (rows wrap)

    for (int it = 0; it < GROUPS_PER_WAVE; ++it) {
        const int g   = gwave + it * WAVES_TOTAL;
        const int idx = g * 64 + lane;
        const float r  = rr[idx];
        const float im = ri[idx];

        float s0 = d0, s1 = d1, s2 = d2, s3 = d3;
        #pragma unroll 16
        for (int j = 0; j < 64; ++j) {
            const float4 c  = c4g[j];            // wave-uniform
            const float4 gg = g4g[j];
            const float zn = fmaf(c.x, r, fmaf(c.y, im, c.z));   // -log2e * z
            const float e  = EXP2(zn);                           // exp(-z)
            const float rc = RCP(1.0f + e);                      // sigmoid(z)
            const float u  = zn * NLN2 * rc;                     // z * sigmoid(z)
            s0 = fmaf(gg.x, u, s0);
            s1 = fmaf(gg.y, u, s1);
            s2 = fmaf(gg.z, u, s2);
            s3 = fmaf(gg.w, u, s3);
            uw[j * 72 + lane] = to_bf16(u);
        }
        const float p0 = EXP2(s0), p1 = EXP2(s1), p2 = EXP2(s2), p3 = EXP2(s3);
        l0 += p0; l1 += p1; l2 += p2; l3 += p3;
        pw[0 * 72 + lane] = to_bf16(p0);
        pw[1 * 72 + lane] = to_bf16(p1);
        pw[2 * 72 + lane] = to_bf16(p2);
        pw[3 * 72 + lane] = to_bf16(p3);
        WG_FENCE();

        // A-frags: A[m=lane&15][k=quad*8+i] = p[h=m][pt=k]; rows 4..15 garbage (ignored)
        const bf16x8 a0 = *(const bf16x8*)(pa);
        const bf16x8 a1 = *(const bf16x8*)(pa + 32);
        #pragma unroll
        for (int tt = 0; tt < 4; ++tt) {
            // B-frags: B[k=quad*8+i][n=lane&15] = u[j=tt*16+n][pt=k]
            const unsigned short* bb = uw + (tt * 16 + (lane & 15)) * 72 + quad * 8;
            acc[tt] = __builtin_amdgcn_mfma_f32_16x16x32_bf16(
                          a0, *(const bf16x8*)(bb), acc[tt], 0, 0, 0);
            acc[tt] = __builtin_amdgcn_mfma_f32_16x16x32_bf16(
                          a1, *(const bf16x8*)(bb + 32), acc[tt], 0, 0, 0);
        }
        WG_FENCE();   // reads done before next iteration's writes
    }

    // l: lane-local partials -> wave reduce
    for (int m = 1; m < 64; m <<= 1) {
        l0 += __shfl_xor(l0, m);
        l1 += __shfl_xor(l1, m);
        l2 += __shfl_xor(l2, m);
        l3 += __shfl_xor(l3, m);
    }

    float* accS = accb + (blockIdx.x & (NSLOT - 1)) * SLOTSTRIDE;
    if (lane == 0) {
        atomicAdd(accS + 0, l0);
        atomicAdd(accS + 1, l1);
        atomicAdd(accS + 2, l2);
        atomicAdd(accS + 3, l3);
    }
    // C layout: col = lane&15, row = quad*4 + reg; rows 0..3 (=h) live in quad 0
    if (lane < 16) {
        #pragma unroll
        for (int tt = 0; tt < 4; ++tt)
            #pragma unroll
            for (int r2 = 0; r2 < 4; ++r2)
                atomicAdd(accS + 4 + r2 * 64 + tt * 16 + lane, acc[tt][r2]);
    }

    // ---- last-block finish ----
    __threadfence();
    __syncthreads();
    __shared__ int isLast;
    if (t == 0) {
        const int old = atomicAdd(cnt, 1);
        isLast = (old == K1_BLOCKS - 1);
    }
    __syncthreads();
    if (!isLast) return;
    __threadfence();   // acquire side of the handshake

    float* red = (float*)&us[0][0];   // 260 floats: [0..3]=l, [4+h*64+k]=T
    float* sb  = red + 260;           // 256
    float* pl  = sb + 256;            // 64

    for (int idx = t; idx < 260; idx += K1_THREADS) {
        float a = 0.0f;
        for (int s = 0; s < NSLOT; ++s)
            a += __hip_atomic_load(accb + s * SLOTSTRIDE + idx,
                                   __ATOMIC_RELAXED, __HIP_MEMORY_SCOPE_AGENT);
        red[idx] = a;
    }
    __syncthreads();

    for (int idx = t; idx < 256; idx += K1_THREADS) {
        const int h = idx >> 6, j = idx & 63;
        const float inv = 1.0f / red[h];
        float a = 0.0f;
        #pragma unroll
        for (int k = 0; k < 64; ++k) a += W2[j * 64 + k] * red[4 + h * 64 + k];
        sb[idx] = fmaf(inv, a, b2[j]);
    }
    __syncthreads();

    if (t < 64) {
        const int h = t >> 4;
        float a = ipb[128 + t];
        #pragma unroll
        for (int d = 0; d < 64; ++d) a += ipw[(128 + t) * 64 + d] * sb[h * 64 + d];
        pl[t] = a;
    }
    __syncthreads();

    if (t < 64) {
        float a = opb[t];
        #pragma unroll
        for (int p = 0; p < 64; ++p) a += opw[t * 64 + p] * pl[p];
        out[t] = a;
    }
}

// ---------------------------------------------------------------------------
extern "C" void kernel_launch(void* const* d_in, const int* in_sizes, int n_in,
                              void* d_out, int out_size, void* d_ws, size_t ws_size,
                              hipStream_t stream)
{
    const float* rr  = (const float*)d_in[0];   // rho_real
    const float* ri  = (const float*)d_in[1];   // rho_imag
    // d_in[2..5]: l_A, l_B, Z_A, Z_B — unused
    const float* W1  = (const float*)d_in[6];
    const float* b1  = (const float*)d_in[7];
    const float* W2  = (const float*)d_in[8];
    const float* b2  = (const float*)d_in[9];
    const float* qy  = (const float*)d_in[10];
    const float* ipw = (const float*)d_in[11];
    const float* ipb = (const float*)d_in[12];
    const float* opw = (const float*)d_in[13];
    const float* opb = (const float*)d_in[14];
    float* ws  = (float*)d_ws;
    float* out = (float*)d_out;

    // zero accumulators + completion counter
    hipMemsetAsync(ws + WS_ACC, 0, (size_t)(NSLOT * SLOTSTRIDE + 1) * sizeof(float), stream);
    setup_kernel<<<64, 64, 0, stream>>>(W1, b1, W2, b2, qy, ipw, ipb, ws);
    main_kernel<<<K1_BLOCKS, K1_THREADS, 0, stream>>>(
        rr, ri,
        (const float4*)(ws + WS_C4), (const float4*)(ws + WS_G4), ws + WS_D,
        ws + WS_ACC, (int*)(ws + WS_CNT),
        W2, b2, ipw, ipb, opw, opb, out);
}

// Round 4
// 143.368 us; speedup vs baseline: 1.2420x; 1.2420x over previous
//
#include <hip/hip_runtime.h>

// ---------------------------------------------------------------------------
// UniversalBlockEncoder: algebraically folded attention pooling.
//
//   u_i = silu(W1 x_i + b1)                 (the only per-point nonlinearity)
//   s_h(i) = g_h . u_i + d_h    with g_h = W2^T (scale Wk_h^T q_h)
//   p = exp(s)  (scores O(3), f32-safe without max-subtraction)
//   T_h = sum_i p_h(i) u_i ,  l_h = sum_i p_h(i)
//   out = Wo ( Wv ( W2 (T/l) + b2 ) + bv ) + bo
//
// R4: R2 structure (scalar phase 2, proven 45us) + packed v_pk_*_f32 phase 1
//     (j-pairs as float2), pair-interleaved constant layout, setup zeroes acc.
// ---------------------------------------------------------------------------

#define LOG2E 1.44269504088896340736f
#define NLN2  (-0.69314718055994530942f)

#if __has_builtin(__builtin_amdgcn_exp2f)
#define EXP2(x) __builtin_amdgcn_exp2f(x)
#else
#define EXP2(x) exp2f(x)
#endif
#if __has_builtin(__builtin_amdgcn_rcpf)
#define RCP(x) __builtin_amdgcn_rcpf(x)
#else
#define RCP(x) (1.0f / (x))
#endif

typedef float v2f __attribute__((ext_vector_type(2)));

// ws float offsets: constants stored pair-interleaved so flat index j works
// for both writer (setup, per-j) and reader (main, v2f at index jp=j/2).
#define WS_CX2 0      // 64 : -log2e*W1[j][0]
#define WS_CY2 64     // 64 : -log2e*W1[j][1]
#define WS_CZ2 128    // 64 : -log2e*b1[j]
#define WS_G02 192    // 64 : log2e*g_0[j]
#define WS_G12 256
#define WS_G22 320
#define WS_G32 384
#define WS_D   448    // 4  : log2e*d_h
#define WS_ACC 512    // NSLOT x SLOTSTRIDE: [0..3]=l_h, [4+h*64+j]=T_h[j]
#define NSLOT      16
#define SLOTSTRIDE 272

#define NPTS       (1024 * 1024)
#define K1_BLOCKS  2048
#define K1_THREADS 128
#define WAVES_TOTAL (K1_BLOCKS * 2)                   // 4096
#define GROUPS_PER_WAVE ((NPTS / 64) / WAVES_TOTAL)   // 4

#define WG_FENCE() __builtin_amdgcn_fence(__ATOMIC_ACQ_REL, "workgroup")

__device__ __forceinline__ unsigned short to_bf16(float x) {
    return (unsigned short)((__float_as_uint(x) + 0x8000u) >> 16);
}

// ---------------------------------------------------------------------------
// Setup: 64 blocks x 64 threads. Every block redundantly computes q and a
// (coalesced); block j computes g[j][h] lane-per-d + shuffle reduce. All
// blocks also cooperatively zero the accumulator slots (replaces memset node).
__global__ void setup_kernel(const float* __restrict__ W1, const float* __restrict__ b1,
                             const float* __restrict__ W2, const float* __restrict__ b2,
                             const float* __restrict__ query,
                             const float* __restrict__ ipw, const float* __restrict__ ipb,
                             float* __restrict__ ws)
{
    __shared__ float qv[64], qs[64], as4[4][64];
    const int t = threadIdx.x;
    const int b = blockIdx.x;     // = output j

    // cooperative zero of the atomic accumulator region
    for (int i = b * 64 + t; i < NSLOT * SLOTSTRIDE; i += 64 * 64)
        ws[WS_ACC + i] = 0.0f;

    qv[t] = query[t];
    __syncthreads();

    // q[t] = ipw row t . query + ipb[t]
    {
        float a = ipb[t];
        #pragma unroll
        for (int k = 0; k < 64; ++k) a = fmaf(ipw[t * 64 + k], qv[k], a);
        qs[t] = a;
    }
    __syncthreads();

    // a_h[t] = 0.25 * sum_m Wk[h*16+m][t] q[h*16+m]   (coalesced across t)
    #pragma unroll
    for (int h = 0; h < 4; ++h) {
        float a = 0.0f;
        #pragma unroll
        for (int m = 0; m < 16; ++m)
            a = fmaf(ipw[(64 + h * 16 + m) * 64 + t], qs[h * 16 + m], a);
        as4[h][t] = 0.25f * a;
    }
    __syncthreads();

    // g[j=b][h] = sum_d a_h[d] W2[d][b] : lane d holds one product, shuffle-reduce
    const float w2 = W2[t * 64 + b];
    float g[4];
    #pragma unroll
    for (int h = 0; h < 4; ++h) {
        float v = as4[h][t] * w2;
        for (int m = 1; m < 64; m <<= 1) v += __shfl_xor(v, m);
        g[h] = v;
    }
    if (t == 0) {
        ws[WS_CX2 + b] = -LOG2E * W1[2 * b];
        ws[WS_CY2 + b] = -LOG2E * W1[2 * b + 1];
        ws[WS_CZ2 + b] = -LOG2E * b1[b];
        ws[WS_G02 + b] = LOG2E * g[0];
        ws[WS_G12 + b] = LOG2E * g[1];
        ws[WS_G22 + b] = LOG2E * g[2];
        ws[WS_G32 + b] = LOG2E * g[3];
    }
    if (b == 0 && t < 4) {
        float d = 0.0f;
        #pragma unroll
        for (int c = 0; c < 64; ++c) d += as4[t][c] * b2[c];
        float qb = 0.0f;
        #pragma unroll
        for (int m = 0; m < 16; ++m) qb += qs[t * 16 + m] * ipb[64 + t * 16 + m];
        ws[WS_D + t] = LOG2E * (d + 0.25f * qb);
    }
}

// ---------------------------------------------------------------------------
// Main: 2 independent waves/block (own LDS halves; fence not barrier).
// Phase 1 (lane = point): j-PAIRS with float2 -> v_pk_fma_f32/v_pk_add_f32/
// v_pk_mul_f32; exp2/rcp stay scalar x2. Stage bf16 u -> LDS [j][pt] str 66.
// Phase 2 (lane = j): scalar outer-product accum (R2-proven, conflict-free).
__global__ __launch_bounds__(K1_THREADS) void main_kernel(
        const float* __restrict__ rr, const float* __restrict__ ri,
        const float* __restrict__ wsc, float* __restrict__ accb)
{
    __shared__ unsigned short us[2][64 * 66];  // u bf16 [j][pt], stride 66
    __shared__ float4 p4s[2][64];

    const int t    = threadIdx.x;
    const int lane = t & 63;
    const int w    = t >> 6;

    const v2f* cx2 = (const v2f*)(wsc + WS_CX2);   // wave-uniform -> s_load
    const v2f* cy2 = (const v2f*)(wsc + WS_CY2);
    const v2f* cz2 = (const v2f*)(wsc + WS_CZ2);
    const v2f* g02 = (const v2f*)(wsc + WS_G02);
    const v2f* g12 = (const v2f*)(wsc + WS_G12);
    const v2f* g22 = (const v2f*)(wsc + WS_G22);
    const v2f* g32 = (const v2f*)(wsc + WS_G32);
    const float d0 = wsc[WS_D + 0], d1 = wsc[WS_D + 1];
    const float d2 = wsc[WS_D + 2], d3 = wsc[WS_D + 3];

    const int gwave = blockIdx.x * 2 + w;
    float l0 = 0, l1 = 0, l2 = 0, l3 = 0;
    float t0 = 0, t1 = 0, t2 = 0, t3 = 0;
    unsigned short* uw = us[w];

    for (int it = 0; it < GROUPS_PER_WAVE; ++it) {
        const int g   = gwave + it * WAVES_TOTAL;
        const int idx = g * 64 + lane;          // exact: covers all NPTS
        const float r  = rr[idx];
        const float im = ri[idx];
        const v2f r2  = {r, r};
        const v2f im2 = {im, im};

        v2f s0v = {d0, 0.f}, s1v = {d1, 0.f}, s2v = {d2, 0.f}, s3v = {d3, 0.f};
        #pragma unroll
        for (int jp = 0; jp < 32; ++jp) {
            const v2f cx = cx2[jp], cy = cy2[jp], cz = cz2[jp];
            const v2f zn = cx * r2 + (cy * im2 + cz);     // 2x v_pk_fma_f32
            v2f e;  e.x  = EXP2(zn.x);  e.y  = EXP2(zn.y);   // exp(-z)
            const v2f op = e + 1.0f;                      // v_pk_add_f32
            v2f rc; rc.x = RCP(op.x);  rc.y = RCP(op.y);  // sigmoid(z)
            const v2f u  = (zn * NLN2) * rc;              // 2x v_pk_mul_f32
            s0v += g02[jp] * u;                           // 4x v_pk_fma_f32
            s1v += g12[jp] * u;
            s2v += g22[jp] * u;
            s3v += g32[jp] * u;
            uw[(2 * jp) * 66 + lane]     = to_bf16(u.x);
            uw[(2 * jp + 1) * 66 + lane] = to_bf16(u.y);
        }
        const float p0 = EXP2(s0v.x + s0v.y);
        const float p1 = EXP2(s1v.x + s1v.y);
        const float p2 = EXP2(s2v.x + s2v.y);
        const float p3 = EXP2(s3v.x + s3v.y);
        l0 += p0; l1 += p1; l2 += p2; l3 += p3;
        p4s[w][lane] = make_float4(p0, p1, p2, p3);
        WG_FENCE();

        // packed read: 2 bf16 points per ds_read_b32; bank (lane+p2)%32 -> 2-way, free
        const unsigned int* urow = (const unsigned int*)(uw + lane * 66);
        #pragma unroll 16
        for (int pp = 0; pp < 32; ++pp) {
            const unsigned int bits = urow[pp];
            const float ulo = __uint_as_float(bits << 16);
            const float uhi = __uint_as_float(bits & 0xFFFF0000u);
            const float4 pa = p4s[w][2 * pp];
            const float4 pb = p4s[w][2 * pp + 1];
            t0 = fmaf(pa.x, ulo, t0); t0 = fmaf(pb.x, uhi, t0);
            t1 = fmaf(pa.y, ulo, t1); t1 = fmaf(pb.y, uhi, t1);
            t2 = fmaf(pa.z, ulo, t2); t2 = fmaf(pb.z, uhi, t2);
            t3 = fmaf(pa.w, ulo, t3); t3 = fmaf(pb.w, uhi, t3);
        }
        WG_FENCE();   // reads done before next iteration's writes
    }

    // l: lane-local partials -> wave reduce
    for (int m = 1; m < 64; m <<= 1) {
        l0 += __shfl_xor(l0, m);
        l1 += __shfl_xor(l1, m);
        l2 += __shfl_xor(l2, m);
        l3 += __shfl_xor(l3, m);
    }

    float* acc = accb + (blockIdx.x & (NSLOT - 1)) * SLOTSTRIDE;
    if (lane == 0) {
        atomicAdd(acc + 0, l0);
        atomicAdd(acc + 1, l1);
        atomicAdd(acc + 2, l2);
        atomicAdd(acc + 3, l3);
    }
    atomicAdd(acc + 4 + 0 * 64 + lane, t0);
    atomicAdd(acc + 4 + 1 * 64 + lane, t1);
    atomicAdd(acc + 4 + 2 * 64 + lane, t2);
    atomicAdd(acc + 4 + 3 * 64 + lane, t3);
}

// ---------------------------------------------------------------------------
__global__ void finish_kernel(const float* __restrict__ W2, const float* __restrict__ b2,
                              const float* __restrict__ ipw, const float* __restrict__ ipb,
                              const float* __restrict__ opw, const float* __restrict__ opb,
                              const float* __restrict__ ws, float* __restrict__ out)
{
    __shared__ float red[260];   // [0..3]=l, [4+h*64+k]=T
    __shared__ float sb[256];    // S-bar per (h, j)
    __shared__ float pl[64];     // pooled
    const int t = threadIdx.x;

    {
        float a = 0.0f;
        for (int s = 0; s < NSLOT; ++s) a += ws[WS_ACC + s * SLOTSTRIDE + t];
        red[t] = a;
        if (t < 4) {
            float a2 = 0.0f;
            for (int s = 0; s < NSLOT; ++s) a2 += ws[WS_ACC + s * SLOTSTRIDE + 256 + t];
            red[256 + t] = a2;
        }
    }
    __syncthreads();

    // S-bar_h[j] = W2[j][:] . (T_h / l_h) + b2[j]
    {
        const int h = t >> 6, j = t & 63;
        const float inv = 1.0f / red[h];
        float a = 0.0f;
        #pragma unroll
        for (int k = 0; k < 64; ++k) a += W2[j * 64 + k] * red[4 + h * 64 + k];
        sb[t] = fmaf(inv, a, b2[j]);
    }
    __syncthreads();

    // pooled[t] = Wv[t][:] . S-bar_h + bv[t]   (Wv = in_proj_w rows 128..191)
    if (t < 64) {
        const int h = t >> 4;
        float a = ipb[128 + t];
        #pragma unroll
        for (int d = 0; d < 64; ++d) a += ipw[(128 + t) * 64 + d] * sb[h * 64 + d];
        pl[t] = a;
    }
    __syncthreads();

    if (t < 64) {
        float a = opb[t];
        #pragma unroll
        for (int p = 0; p < 64; ++p) a += opw[t * 64 + p] * pl[p];
        out[t] = a;
    }
}

// ---------------------------------------------------------------------------
extern "C" void kernel_launch(void* const* d_in, const int* in_sizes, int n_in,
                              void* d_out, int out_size, void* d_ws, size_t ws_size,
                              hipStream_t stream)
{
    const float* rr  = (const float*)d_in[0];   // rho_real
    const float* ri  = (const float*)d_in[1];   // rho_imag
    // d_in[2..5]: l_A, l_B, Z_A, Z_B — unused by the reference
    const float* W1  = (const float*)d_in[6];
    const float* b1  = (const float*)d_in[7];
    const float* W2  = (const float*)d_in[8];
    const float* b2  = (const float*)d_in[9];
    const float* qy  = (const float*)d_in[10];
    const float* ipw = (const float*)d_in[11];
    const float* ipb = (const float*)d_in[12];
    const float* opw = (const float*)d_in[13];
    const float* opb = (const float*)d_in[14];
    float* ws  = (float*)d_ws;
    float* out = (float*)d_out;

    setup_kernel<<<64, 64, 0, stream>>>(W1, b1, W2, b2, qy, ipw, ipb, ws);
    main_kernel<<<K1_BLOCKS, K1_THREADS, 0, stream>>>(rr, ri, ws, ws + WS_ACC);
    finish_kernel<<<1, 256, 0, stream>>>(W2, b2, ipw, ipb, opw, opb, ws, out);
}

// Round 5
// 132.431 us; speedup vs baseline: 1.3445x; 1.0826x over previous
//
#include <hip/hip_runtime.h>

// ---------------------------------------------------------------------------
// UniversalBlockEncoder: algebraically folded attention pooling.
//
//   u_i = silu(W1 x_i + b1)                 (the only per-point nonlinearity)
//   s_h(i) = g_h . u_i + d_h    with g_h = W2^T (scale Wk_h^T q_h)
//   p = exp(s)  (scores O(3), f32-safe without max-subtraction)
//   T_h = sum_i p_h(i) u_i ,  l_h = sum_i p_h(i)
//   out = Wo ( Wv ( W2 (T/l) + b2 ) + bv ) + bo
//
// R5: R2 structure + (a) pure-LDS s_waitcnt instead of acq_rel fence (which
//     drains vmcnt and exposed global-load latency every group), (b) all
//     rho loads hoisted to kernel entry, (c) NLN2 folded into g / epilogue
//     (stage ub = zn*rc; g' = -g; finish scales by NLN2/l).
// ---------------------------------------------------------------------------

#define LOG2E 1.44269504088896340736f
#define NLN2  (-0.69314718055994530942f)

#if __has_builtin(__builtin_amdgcn_exp2f)
#define EXP2(x) __builtin_amdgcn_exp2f(x)
#else
#define EXP2(x) exp2f(x)
#endif
#if __has_builtin(__builtin_amdgcn_rcpf)
#define RCP(x) __builtin_amdgcn_rcpf(x)
#else
#define RCP(x) (1.0f / (x))
#endif

// LDS-only ordering within a wave (each wave reads only its own LDS half;
// wave lockstep means lgkmcnt(0) is a sufficient producer-consumer barrier).
// Unlike __builtin_amdgcn_fence(workgroup), this does NOT drain vmcnt.
#define LDS_WAIT() asm volatile("s_waitcnt lgkmcnt(0)" ::: "memory")

// workspace float offsets
#define WS_C4   0      // 64 x float4 : {-log2e*W1[j][0], -log2e*W1[j][1], -log2e*b1[j], 0}
#define WS_G4   256    // 64 x float4 : -g_h[j]              (NLN2*LOG2E = -1 fold)
#define WS_D    512    // 4           : log2e * d_h
#define WS_ACC  768    // NSLOT x SLOTSTRIDE: [0..3]=l_h, [4+h*64+j]=T'_h[j]
#define NSLOT      16
#define SLOTSTRIDE 272

#define NPTS       (1024 * 1024)
#define K1_BLOCKS  2048
#define K1_THREADS 128
#define WAVES_TOTAL (K1_BLOCKS * 2)                   // 4096
#define GROUPS_PER_WAVE ((NPTS / 64) / WAVES_TOTAL)   // 4

__device__ __forceinline__ unsigned short to_bf16(float x) {
    return (unsigned short)((__float_as_uint(x) + 0x8000u) >> 16);
}

// ---------------------------------------------------------------------------
// Setup: 64 blocks x 64 threads. Every block redundantly computes q and a
// (coalesced); block j computes g[j][h] lane-per-d + shuffle reduce. All
// blocks cooperatively zero the accumulator slots.
__global__ void setup_kernel(const float* __restrict__ W1, const float* __restrict__ b1,
                             const float* __restrict__ W2, const float* __restrict__ b2,
                             const float* __restrict__ query,
                             const float* __restrict__ ipw, const float* __restrict__ ipb,
                             float* __restrict__ ws)
{
    __shared__ float qv[64], qs[64], as4[4][64];
    const int t = threadIdx.x;
    const int b = blockIdx.x;     // = output j

    for (int i = b * 64 + t; i < NSLOT * SLOTSTRIDE; i += 64 * 64)
        ws[WS_ACC + i] = 0.0f;

    qv[t] = query[t];
    __syncthreads();

    // q[t] = ipw row t . query + ipb[t]
    {
        float a = ipb[t];
        #pragma unroll
        for (int k = 0; k < 64; ++k) a = fmaf(ipw[t * 64 + k], qv[k], a);
        qs[t] = a;
    }
    __syncthreads();

    // a_h[t] = 0.25 * sum_m Wk[h*16+m][t] q[h*16+m]   (coalesced across t)
    #pragma unroll
    for (int h = 0; h < 4; ++h) {
        float a = 0.0f;
        #pragma unroll
        for (int m = 0; m < 16; ++m)
            a = fmaf(ipw[(64 + h * 16 + m) * 64 + t], qs[h * 16 + m], a);
        as4[h][t] = 0.25f * a;
    }
    __syncthreads();

    // g[j=b][h] = sum_d a_h[d] W2[d][b] : lane d holds one product, shuffle-reduce
    const float w2 = W2[t * 64 + b];
    float g[4];
    #pragma unroll
    for (int h = 0; h < 4; ++h) {
        float v = as4[h][t] * w2;
        for (int m = 1; m < 64; m <<= 1) v += __shfl_xor(v, m);
        g[h] = v;
    }
    if (t == 0) {
        ws[WS_G4 + b * 4 + 0] = -g[0];    // -g: LOG2E*NLN2 fold
        ws[WS_G4 + b * 4 + 1] = -g[1];
        ws[WS_G4 + b * 4 + 2] = -g[2];
        ws[WS_G4 + b * 4 + 3] = -g[3];
        ws[WS_C4 + b * 4 + 0] = -LOG2E * W1[2 * b];
        ws[WS_C4 + b * 4 + 1] = -LOG2E * W1[2 * b + 1];
        ws[WS_C4 + b * 4 + 2] = -LOG2E * b1[b];
        ws[WS_C4 + b * 4 + 3] = 0.0f;
    }
    if (b == 0 && t < 4) {
        float d = 0.0f;
        #pragma unroll
        for (int c = 0; c < 64; ++c) d += as4[t][c] * b2[c];
        float qb = 0.0f;
        #pragma unroll
        for (int m = 0; m < 16; ++m) qb += qs[t * 16 + m] * ipb[64 + t * 16 + m];
        ws[WS_D + t] = LOG2E * (d + 0.25f * qb);
    }
}

// ---------------------------------------------------------------------------
// Main: 2 independent waves/block (own LDS halves; pure-lgkm waits).
// Phase 1 (lane = point): ub_j = zn*rc via silu pieces, scores, bf16 ub -> LDS.
// Phase 2 (lane = j): scalar outer-product accumulate (b32-packed reads).
__global__ __launch_bounds__(K1_THREADS) void main_kernel(
        const float* __restrict__ rr, const float* __restrict__ ri,
        const float4* __restrict__ c4g, const float4* __restrict__ g4g,
        const float* __restrict__ dvec, float* __restrict__ accb)
{
    __shared__ unsigned short us[2][64 * 66];  // ub bf16 [j][pt], stride 66
    __shared__ float4 p4s[2][64];

    const int t    = threadIdx.x;
    const int lane = t & 63;
    const int w    = t >> 6;

    const float d0 = dvec[0], d1 = dvec[1], d2 = dvec[2], d3 = dvec[3];

    const int gwave = blockIdx.x * 2 + w;
    float l0 = 0, l1 = 0, l2 = 0, l3 = 0;
    float t0 = 0, t1 = 0, t2 = 0, t3 = 0;
    unsigned short* uw = us[w];

    // hoist ALL global loads to kernel entry: no vmem waits inside the loop
    float rv[GROUPS_PER_WAVE], iv[GROUPS_PER_WAVE];
    #pragma unroll
    for (int it = 0; it < GROUPS_PER_WAVE; ++it) {
        const int idx = (gwave + it * WAVES_TOTAL) * 64 + lane;
        rv[it] = rr[idx];
        iv[it] = ri[idx];
    }

    for (int it = 0; it < GROUPS_PER_WAVE; ++it) {
        const float r  = rv[it];
        const float im = iv[it];

        float s0 = d0, s1 = d1, s2 = d2, s3 = d3;
        #pragma unroll 16
        for (int j = 0; j < 64; ++j) {
            const float4 c  = c4g[j];            // wave-uniform
            const float4 gg = g4g[j];
            const float zn = fmaf(c.x, r, fmaf(c.y, im, c.z));   // -log2e * z
            const float e  = EXP2(zn);                           // exp(-z)
            const float rc = RCP(1.0f + e);                      // sigmoid(z)
            const float ub = zn * rc;            // = u / NLN2  (fold)
            s0 = fmaf(gg.x, ub, s0);
            s1 = fmaf(gg.y, ub, s1);
            s2 = fmaf(gg.z, ub, s2);
            s3 = fmaf(gg.w, ub, s3);
            uw[j * 66 + lane] = to_bf16(ub);
        }
        const float p0 = EXP2(s0), p1 = EXP2(s1), p2 = EXP2(s2), p3 = EXP2(s3);
        l0 += p0; l1 += p1; l2 += p2; l3 += p3;
        p4s[w][lane] = make_float4(p0, p1, p2, p3);
        LDS_WAIT();

        // packed read: 2 bf16 points per ds_read_b32; bank (lane+pp)%32 -> 2-way, free
        const unsigned int* urow = (const unsigned int*)(uw + lane * 66);
        #pragma unroll 16
        for (int pp = 0; pp < 32; ++pp) {
            const unsigned int bits = urow[pp];
            const float ulo = __uint_as_float(bits << 16);
            const float uhi = __uint_as_float(bits & 0xFFFF0000u);
            const float4 pa = p4s[w][2 * pp];
            const float4 pb = p4s[w][2 * pp + 1];
            t0 = fmaf(pa.x, ulo, t0); t0 = fmaf(pb.x, uhi, t0);
            t1 = fmaf(pa.y, ulo, t1); t1 = fmaf(pb.y, uhi, t1);
            t2 = fmaf(pa.z, ulo, t2); t2 = fmaf(pb.z, uhi, t2);
            t3 = fmaf(pa.w, ulo, t3); t3 = fmaf(pb.w, uhi, t3);
        }
        LDS_WAIT();   // reads done before next iteration's writes (WAR)
    }

    // l: lane-local partials -> wave reduce
    for (int m = 1; m < 64; m <<= 1) {
        l0 += __shfl_xor(l0, m);
        l1 += __shfl_xor(l1, m);
        l2 += __shfl_xor(l2, m);
        l3 += __shfl_xor(l3, m);
    }

    float* acc = accb + (blockIdx.x & (NSLOT - 1)) * SLOTSTRIDE;
    if (lane == 0) {
        atomicAdd(acc + 0, l0);
        atomicAdd(acc + 1, l1);
        atomicAdd(acc + 2, l2);
        atomicAdd(acc + 3, l3);
    }
    atomicAdd(acc + 4 + 0 * 64 + lane, t0);
    atomicAdd(acc + 4 + 1 * 64 + lane, t1);
    atomicAdd(acc + 4 + 2 * 64 + lane, t2);
    atomicAdd(acc + 4 + 3 * 64 + lane, t3);
}

// ---------------------------------------------------------------------------
__global__ void finish_kernel(const float* __restrict__ W2, const float* __restrict__ b2,
                              const float* __restrict__ ipw, const float* __restrict__ ipb,
                              const float* __restrict__ opw, const float* __restrict__ opb,
                              const float* __restrict__ ws, float* __restrict__ out)
{
    __shared__ float red[260];   // [0..3]=l, [4+h*64+k]=T'
    __shared__ float sb[256];    // S-bar per (h, j)
    __shared__ float pl[64];     // pooled
    const int t = threadIdx.x;

    {
        float a = 0.0f;
        for (int s = 0; s < NSLOT; ++s) a += ws[WS_ACC + s * SLOTSTRIDE + t];
        red[t] = a;
        if (t < 4) {
            float a2 = 0.0f;
            for (int s = 0; s < NSLOT; ++s) a2 += ws[WS_ACC + s * SLOTSTRIDE + 256 + t];
            red[256 + t] = a2;
        }
    }
    __syncthreads();

    // S-bar_h[j] = W2[j][:] . (NLN2 * T'_h / l_h) + b2[j]
    {
        const int h = t >> 6, j = t & 63;
        const float inv = NLN2 / red[h];     // NLN2 fold applied here
        float a = 0.0f;
        #pragma unroll
        for (int k = 0; k < 64; ++k) a += W2[j * 64 + k] * red[4 + h * 64 + k];
        sb[t] = fmaf(inv, a, b2[j]);
    }
    __syncthreads();

    // pooled[t] = Wv[t][:] . S-bar_h + bv[t]   (Wv = in_proj_w rows 128..191)
    if (t < 64) {
        const int h = t >> 4;
        float a = ipb[128 + t];
        #pragma unroll
        for (int d = 0; d < 64; ++d) a += ipw[(128 + t) * 64 + d] * sb[h * 64 + d];
        pl[t] = a;
    }
    __syncthreads();

    if (t < 64) {
        float a = opb[t];
        #pragma unroll
        for (int p = 0; p < 64; ++p) a += opw[t * 64 + p] * pl[p];
        out[t] = a;
    }
}

// ---------------------------------------------------------------------------
extern "C" void kernel_launch(void* const* d_in, const int* in_sizes, int n_in,
                              void* d_out, int out_size, void* d_ws, size_t ws_size,
                              hipStream_t stream)
{
    const float* rr  = (const float*)d_in[0];   // rho_real
    const float* ri  = (const float*)d_in[1];   // rho_imag
    // d_in[2..5]: l_A, l_B, Z_A, Z_B — unused by the reference
    const float* W1  = (const float*)d_in[6];
    const float* b1  = (const float*)d_in[7];
    const float* W2  = (const float*)d_in[8];
    const float* b2  = (const float*)d_in[9];
    const float* qy  = (const float*)d_in[10];
    const float* ipw = (const float*)d_in[11];
    const float* ipb = (const float*)d_in[12];
    const float* opw = (const float*)d_in[13];
    const float* opb = (const float*)d_in[14];
    float* ws  = (float*)d_ws;
    float* out = (float*)d_out;

    setup_kernel<<<64, 64, 0, stream>>>(W1, b1, W2, b2, qy, ipw, ipb, ws);
    main_kernel<<<K1_BLOCKS, K1_THREADS, 0, stream>>>(
        rr, ri,
        (const float4*)(ws + WS_C4), (const float4*)(ws + WS_G4),
        ws + WS_D, ws + WS_ACC);
    finish_kernel<<<1, 256, 0, stream>>>(W2, b2, ipw, ipb, opw, opb, ws, out);
}